// Round 2
// baseline (2893.092 us; speedup 1.0000x reference)
//
#include <hip/hip_runtime.h>

#define DD 128   // feature dim (in == out)
#define BM 64    // GEMM rows per block
#define BK 32    // GEMM k-tile

// ---------------------------------------------------------------------------
// Detect whether edge_index arrived as int32 or int64.
// If int64 (values < 50000), every u64 word < 2^32. If int32, u64 words are
// pairs (idx_even, idx_odd<<32) and odd indices are ~never all zero.
__global__ void detect_kernel(const unsigned long long* __restrict__ ei,
                              int n64, int* __restrict__ flag) {
    if (threadIdx.x == 0 && blockIdx.x == 0) {
        int is64 = 1;
        for (int i = 0; i < n64; ++i) {
            if (ei[i] >= (1ULL << 32)) { is64 = 0; break; }
        }
        *flag = is64;   // 1 = int64, 0 = int32
    }
}

// ---------------------------------------------------------------------------
// Transpose both weight matrices: Wt[k][col] = W[col][k], so the GEMM reads
// W rows coalesced / LDS-conflict-free.
__global__ void transpose_kernel(const float* __restrict__ Ws,
                                 const float* __restrict__ Wn,
                                 float* __restrict__ Wts,
                                 float* __restrict__ Wtn) {
    int idx = blockIdx.x * blockDim.x + threadIdx.x;
    int i = idx & (DD * DD - 1);
    int col = i >> 7;
    int k = i & (DD - 1);
    if (idx < DD * DD)          Wts[k * DD + col] = Ws[i];
    else if (idx < 2 * DD * DD) Wtn[k * DD + col] = Wn[i];
}

// ---------------------------------------------------------------------------
// Symmetrized scatter-add: for each edge (s,d), nei[d] += fea[s] and
// nei[s] += fea[d]. 32 lanes per edge-endpoint row, float4 per lane.
__global__ void scatter_kernel(const float* __restrict__ fea,
                               const void* __restrict__ ei_raw,
                               float* __restrict__ nei,
                               int E, const int* __restrict__ flag) {
    long long r = (long long)blockIdx.x * 8 + (threadIdx.x >> 5);
    if (r >= 2LL * E) return;
    int lr = threadIdx.x & 31;
    int e = (int)(r < E ? r : r - E);
    int s, d;
    if (*flag) {
        const long long* ei = (const long long*)ei_raw;
        s = (int)ei[e];
        d = (int)ei[E + e];
    } else {
        const int* ei = (const int*)ei_raw;
        s = ei[e];
        d = ei[E + e];
    }
    if (r >= E) { int t = s; s = d; d = t; }

    const float4 v = *reinterpret_cast<const float4*>(fea + (size_t)s * DD + lr * 4);
    float* p = nei + (size_t)d * DD + lr * 4;
    unsafeAtomicAdd(p + 0, v.x);
    unsafeAtomicAdd(p + 1, v.y);
    unsafeAtomicAdd(p + 2, v.z);
    unsafeAtomicAdd(p + 3, v.w);
}

// ---------------------------------------------------------------------------
// Fused dual GEMM + bias: out = fea @ Ws^T + nei @ Wn^T + (b_self + b_neig).
// Block: 256 threads -> 64 rows x 128 cols. Thread: 8 rows x 4 cols.
// W tiles read from LDS as float4 (conflict-free); A reads are broadcast.
__launch_bounds__(256)
__global__ void gemm_kernel(const float* __restrict__ fea,
                            const float* __restrict__ nei,
                            const float* __restrict__ Wts,
                            const float* __restrict__ Wtn,
                            const float* __restrict__ bs,
                            const float* __restrict__ bn,
                            float* __restrict__ out, int M) {
    __shared__ float Fs[BM][BK + 4];
    __shared__ float Ns[BM][BK + 4];
    __shared__ float WsT[BK][DD];
    __shared__ float WnT[BK][DD];

    const int t = threadIdx.x;
    const int cg = t & 31;   // col group: cols cg*4 .. cg*4+3
    const int rg = t >> 5;   // row group: rows rg*8 .. rg*8+7
    const int row0 = blockIdx.x * BM;

    float4 acc[8];
#pragma unroll
    for (int r = 0; r < 8; ++r) acc[r] = make_float4(0.f, 0.f, 0.f, 0.f);

    for (int kb = 0; kb < DD; kb += BK) {
        // stage fea/nei tiles: 64 rows x 32 k = 512 float4 each
#pragma unroll
        for (int j = 0; j < 2; ++j) {
            int idx = t + j * 256;           // 0..511
            int row = idx >> 3;              // 0..63
            int seg = idx & 7;               // 0..7
            int grow = row0 + row;
            float4 fv = make_float4(0.f, 0.f, 0.f, 0.f);
            float4 nv = make_float4(0.f, 0.f, 0.f, 0.f);
            if (grow < M) {
                fv = *reinterpret_cast<const float4*>(fea + (size_t)grow * DD + kb + seg * 4);
                nv = *reinterpret_cast<const float4*>(nei + (size_t)grow * DD + kb + seg * 4);
            }
            *reinterpret_cast<float4*>(&Fs[row][seg * 4]) = fv;
            *reinterpret_cast<float4*>(&Ns[row][seg * 4]) = nv;
        }
        // stage W tiles: 32 k x 128 cols = 1024 float4 each
#pragma unroll
        for (int j = 0; j < 4; ++j) {
            int idx = t + j * 256;           // 0..1023
            int kk = idx >> 5;               // 0..31
            int seg = idx & 31;              // 0..31
            *reinterpret_cast<float4*>(&WsT[kk][seg * 4]) =
                *reinterpret_cast<const float4*>(Wts + (size_t)(kb + kk) * DD + seg * 4);
            *reinterpret_cast<float4*>(&WnT[kk][seg * 4]) =
                *reinterpret_cast<const float4*>(Wtn + (size_t)(kb + kk) * DD + seg * 4);
        }
        __syncthreads();

#pragma unroll
        for (int kk = 0; kk < BK; ++kk) {
            float4 wsv = *reinterpret_cast<const float4*>(&WsT[kk][cg * 4]);
            float4 wnv = *reinterpret_cast<const float4*>(&WnT[kk][cg * 4]);
#pragma unroll
            for (int r = 0; r < 8; ++r) {
                float a = Fs[rg * 8 + r][kk];
                float b = Ns[rg * 8 + r][kk];
                acc[r].x += a * wsv.x + b * wnv.x;
                acc[r].y += a * wsv.y + b * wnv.y;
                acc[r].z += a * wsv.z + b * wnv.z;
                acc[r].w += a * wsv.w + b * wnv.w;
            }
        }
        __syncthreads();
    }

    float4 bsv = *reinterpret_cast<const float4*>(bs + cg * 4);
    float4 bnv = *reinterpret_cast<const float4*>(bn + cg * 4);
    float4 bias = make_float4(bsv.x + bnv.x, bsv.y + bnv.y, bsv.z + bnv.z, bsv.w + bnv.w);
#pragma unroll
    for (int r = 0; r < 8; ++r) {
        int grow = row0 + rg * 8 + r;
        if (grow < M) {
            float4 o = make_float4(acc[r].x + bias.x, acc[r].y + bias.y,
                                   acc[r].z + bias.z, acc[r].w + bias.w);
            *reinterpret_cast<float4*>(out + (size_t)grow * DD + cg * 4) = o;
        }
    }
}

// ---------------------------------------------------------------------------
extern "C" void kernel_launch(void* const* d_in, const int* in_sizes, int n_in,
                              void* d_out, int out_size, void* d_ws, size_t ws_size,
                              hipStream_t stream) {
    const float* fea = (const float*)d_in[0];
    const void*  ei  = d_in[1];
    const float* Ws  = (const float*)d_in[2];
    const float* bsv = (const float*)d_in[3];
    const float* Wn  = (const float*)d_in[4];
    const float* bnv = (const float*)d_in[5];

    const int M = in_sizes[0] / DD;      // 50000 nodes
    const int E = in_sizes[1] / 2;       // 800000 edges
    float* out = (float*)d_out;

    char* ws = (char*)d_ws;
    int* flag = (int*)ws;                           // 256 B reserved
    float* Wts = (float*)(ws + 256);                // 64 KB
    float* Wtn = Wts + DD * DD;                     // 64 KB
    size_t nei_off = 256 + (size_t)2 * DD * DD * sizeof(float);
    size_t nei_bytes = (size_t)M * DD * sizeof(float);
    float* nei = (ws_size >= nei_off + nei_bytes) ? (float*)(ws + nei_off)
                                                  : out;  // in-place fallback

    detect_kernel<<<1, 64, 0, stream>>>((const unsigned long long*)ei,
                                        E < 512 ? E : 512, flag);
    hipMemsetAsync(nei, 0, nei_bytes, stream);
    transpose_kernel<<<(2 * DD * DD + 255) / 256, 256, 0, stream>>>(Ws, Wn, Wts, Wtn);

    long long rows = 2LL * E;
    int sblocks = (int)((rows + 7) / 8);
    scatter_kernel<<<sblocks, 256, 0, stream>>>(fea, ei, nei, E, flag);

    int gblocks = (M + BM - 1) / BM;
    gemm_kernel<<<gblocks, 256, 0, stream>>>(fea, nei, Wts, Wtn, bsv, bnv, out, M);
}

// Round 4
// 472.062 us; speedup vs baseline: 6.1286x; 6.1286x over previous
//
#include <hip/hip_runtime.h>

#define DD 128   // feature dim (in == out)
#define BM 64    // GEMM rows per block
#define BK 32    // GEMM k-tile

// ---------------------------------------------------------------------------
// Detect whether edge_index arrived as int32 or int64 (parallel, ballot).
// int64 node ids < 50000 => every u64 word < 2^32. int32 delivery => words are
// (even_idx, odd_idx<<32) pairs and some odd idx is nonzero w.p. ~1.
__global__ void detect_kernel(const unsigned long long* __restrict__ ei,
                              int n64, int* __restrict__ flag) {
    int i = threadIdx.x;  // 64 threads
    bool big = (i < n64) && (ei[i] >= (1ULL << 32));
    unsigned long long b = __ballot(big);
    if (i == 0) *flag = (b == 0ULL) ? 1 : 0;   // 1 = int64, 0 = int32
}

// ---------------------------------------------------------------------------
__global__ void transpose_kernel(const float* __restrict__ Ws,
                                 const float* __restrict__ Wn,
                                 float* __restrict__ Wts,
                                 float* __restrict__ Wtn) {
    int idx = blockIdx.x * blockDim.x + threadIdx.x;
    int i = idx & (DD * DD - 1);
    int col = i >> 7;
    int k = i & (DD - 1);
    if (idx < DD * DD)          Wts[k * DD + col] = Ws[i];
    else if (idx < 2 * DD * DD) Wtn[k * DD + col] = Wn[i];
}

// ---------------------------------------------------------------------------
// Endpoint i in [0,2E):  s = ei[i];  d = ei[i<E ? i+E : i-E].
__device__ __forceinline__ void endpoint(const void* ei_raw, int flag, int E,
                                         int i, int& s, int& d) {
    int di = (i < E) ? i + E : i - E;
    if (flag) {
        const long long* ei = (const long long*)ei_raw;
        s = (int)ei[i]; d = (int)ei[di];
    } else {
        const int* ei = (const int*)ei_raw;
        s = ei[i]; d = ei[di];
    }
}

__global__ void hist_kernel(const void* __restrict__ ei_raw,
                            int* __restrict__ deg, int E,
                            const int* __restrict__ flag) {
    int i = blockIdx.x * blockDim.x + threadIdx.x;
    if (i >= 2 * E) return;
    int s, d; endpoint(ei_raw, *flag, E, i, s, d);
    atomicAdd(&deg[d], 1);
}

// ---------------------------------------------------------------------------
// Exclusive scan of deg[N] -> off[N+1], 1024 elems per block.
__global__ void scan1_kernel(const int* __restrict__ deg, int* __restrict__ off,
                             int* __restrict__ bsum, int N) {
    __shared__ int sd[256];
    int base = blockIdx.x * 1024;
    int t = threadIdx.x;
    int v[4]; int s = 0;
#pragma unroll
    for (int j = 0; j < 4; ++j) {
        int idx = base + t * 4 + j;
        v[j] = (idx < N) ? deg[idx] : 0;
        s += v[j];
    }
    sd[t] = s; __syncthreads();
    for (int o = 1; o < 256; o <<= 1) {
        int x = (t >= o) ? sd[t - o] : 0;
        __syncthreads();
        sd[t] += x;
        __syncthreads();
    }
    int run = sd[t] - s;                 // exclusive prefix of this thread
    if (t == 255) bsum[blockIdx.x] = sd[255];
#pragma unroll
    for (int j = 0; j < 4; ++j) {
        int idx = base + t * 4 + j;
        if (idx < N) off[idx] = run;
        run += v[j];
    }
}

__global__ void scan2_kernel(int* __restrict__ bsum, int NB,
                             int* __restrict__ total) {
    __shared__ int sd[256];
    int t = threadIdx.x;
    int v = (t < NB) ? bsum[t] : 0;
    sd[t] = v; __syncthreads();
    for (int o = 1; o < 256; o <<= 1) {
        int x = (t >= o) ? sd[t - o] : 0;
        __syncthreads();
        sd[t] += x;
        __syncthreads();
    }
    if (t < NB) bsum[t] = sd[t] - v;     // exclusive
    if (t == 255) *total = sd[255];
}

__global__ void scan3_kernel(int* __restrict__ off, const int* __restrict__ bsum,
                             int N) {
    int i = blockIdx.x * blockDim.x + threadIdx.x;
    if (i < N) off[i] += bsum[i >> 10];
}

// ---------------------------------------------------------------------------
__global__ void fill_kernel(const void* __restrict__ ei_raw,
                            const int* __restrict__ off,
                            int* __restrict__ cursor, int* __restrict__ list,
                            int E, const int* __restrict__ flag) {
    int i = blockIdx.x * blockDim.x + threadIdx.x;
    if (i >= 2 * E) return;
    int s, d; endpoint(ei_raw, *flag, E, i, s, d);
    int pos = atomicAdd(&cursor[d], 1);
    list[off[d] + pos] = s;
}

// ---------------------------------------------------------------------------
// One wave per node: register-accumulate all neighbor rows, single write.
__launch_bounds__(256)
__global__ void gather_kernel(const float* __restrict__ fea,
                              const int* __restrict__ off,
                              const int* __restrict__ list,
                              float* __restrict__ nei, int N) {
    int w = (int)((blockIdx.x * 256 + threadIdx.x) >> 6);  // node = global wave
    if (w >= N) return;
    int lane = threadIdx.x & 63;
    int start = off[w], end = off[w + 1];
    float2 acc = make_float2(0.f, 0.f);
    const float* base = fea + (size_t)lane * 2;
    int j = start;
    for (; j + 4 <= end; j += 4) {
        int s0 = list[j], s1 = list[j + 1], s2 = list[j + 2], s3 = list[j + 3];
        float2 a = *reinterpret_cast<const float2*>(base + (size_t)s0 * DD);
        float2 b = *reinterpret_cast<const float2*>(base + (size_t)s1 * DD);
        float2 c = *reinterpret_cast<const float2*>(base + (size_t)s2 * DD);
        float2 e = *reinterpret_cast<const float2*>(base + (size_t)s3 * DD);
        acc.x += a.x + b.x + c.x + e.x;
        acc.y += a.y + b.y + c.y + e.y;
    }
    for (; j < end; ++j) {
        int s0 = list[j];
        float2 a = *reinterpret_cast<const float2*>(base + (size_t)s0 * DD);
        acc.x += a.x; acc.y += a.y;
    }
    *reinterpret_cast<float2*>(nei + (size_t)w * DD + lane * 2) = acc;
}

// ---------------------------------------------------------------------------
// Fallback symmetrized atomic scatter (round-2 proven path).
__global__ void scatter_kernel(const float* __restrict__ fea,
                               const void* __restrict__ ei_raw,
                               float* __restrict__ nei,
                               int E, const int* __restrict__ flag) {
    long long r = (long long)blockIdx.x * 8 + (threadIdx.x >> 5);
    if (r >= 2LL * E) return;
    int lr = threadIdx.x & 31;
    int i = (int)r;
    int s, d; endpoint(ei_raw, *flag, E, i, s, d);
    const float4 v = *reinterpret_cast<const float4*>(fea + (size_t)s * DD + lr * 4);
    float* p = nei + (size_t)d * DD + lr * 4;
    unsafeAtomicAdd(p + 0, v.x);
    unsafeAtomicAdd(p + 1, v.y);
    unsafeAtomicAdd(p + 2, v.z);
    unsafeAtomicAdd(p + 3, v.w);
}

// ---------------------------------------------------------------------------
// Fused dual GEMM + bias: out = fea @ Ws^T + nei @ Wn^T + (b_self + b_neig).
__launch_bounds__(256)
__global__ void gemm_kernel(const float* __restrict__ fea,
                            const float* __restrict__ nei,
                            const float* __restrict__ Wts,
                            const float* __restrict__ Wtn,
                            const float* __restrict__ bs,
                            const float* __restrict__ bn,
                            float* __restrict__ out, int M) {
    __shared__ float Fs[BM][BK + 4];
    __shared__ float Ns[BM][BK + 4];
    __shared__ float WsT[BK][DD];
    __shared__ float WnT[BK][DD];

    const int t = threadIdx.x;
    const int cg = t & 31;
    const int rg = t >> 5;
    const int row0 = blockIdx.x * BM;

    float4 acc[8];
#pragma unroll
    for (int r = 0; r < 8; ++r) acc[r] = make_float4(0.f, 0.f, 0.f, 0.f);

    for (int kb = 0; kb < DD; kb += BK) {
#pragma unroll
        for (int j = 0; j < 2; ++j) {
            int idx = t + j * 256;
            int row = idx >> 3;
            int seg = idx & 7;
            int grow = row0 + row;
            float4 fv = make_float4(0.f, 0.f, 0.f, 0.f);
            float4 nv = make_float4(0.f, 0.f, 0.f, 0.f);
            if (grow < M) {
                fv = *reinterpret_cast<const float4*>(fea + (size_t)grow * DD + kb + seg * 4);
                nv = *reinterpret_cast<const float4*>(nei + (size_t)grow * DD + kb + seg * 4);
            }
            *reinterpret_cast<float4*>(&Fs[row][seg * 4]) = fv;
            *reinterpret_cast<float4*>(&Ns[row][seg * 4]) = nv;
        }
#pragma unroll
        for (int j = 0; j < 4; ++j) {
            int idx = t + j * 256;
            int kk = idx >> 5;
            int seg = idx & 31;
            *reinterpret_cast<float4*>(&WsT[kk][seg * 4]) =
                *reinterpret_cast<const float4*>(Wts + (size_t)(kb + kk) * DD + seg * 4);
            *reinterpret_cast<float4*>(&WnT[kk][seg * 4]) =
                *reinterpret_cast<const float4*>(Wtn + (size_t)(kb + kk) * DD + seg * 4);
        }
        __syncthreads();

#pragma unroll
        for (int kk = 0; kk < BK; ++kk) {
            float4 wsv = *reinterpret_cast<const float4*>(&WsT[kk][cg * 4]);
            float4 wnv = *reinterpret_cast<const float4*>(&WnT[kk][cg * 4]);
#pragma unroll
            for (int r = 0; r < 8; ++r) {
                float a = Fs[rg * 8 + r][kk];
                float b = Ns[rg * 8 + r][kk];
                acc[r].x += a * wsv.x + b * wnv.x;
                acc[r].y += a * wsv.y + b * wnv.y;
                acc[r].z += a * wsv.z + b * wnv.z;
                acc[r].w += a * wsv.w + b * wnv.w;
            }
        }
        __syncthreads();
    }

    float4 bsv = *reinterpret_cast<const float4*>(bs + cg * 4);
    float4 bnv = *reinterpret_cast<const float4*>(bn + cg * 4);
    float4 bias = make_float4(bsv.x + bnv.x, bsv.y + bnv.y, bsv.z + bnv.z, bsv.w + bnv.w);
#pragma unroll
    for (int r = 0; r < 8; ++r) {
        int grow = row0 + rg * 8 + r;
        if (grow < M) {
            float4 o = make_float4(acc[r].x + bias.x, acc[r].y + bias.y,
                                   acc[r].z + bias.z, acc[r].w + bias.w);
            *reinterpret_cast<float4*>(out + (size_t)grow * DD + cg * 4) = o;
        }
    }
}

// ---------------------------------------------------------------------------
extern "C" void kernel_launch(void* const* d_in, const int* in_sizes, int n_in,
                              void* d_out, int out_size, void* d_ws, size_t ws_size,
                              hipStream_t stream) {
    const float* fea = (const float*)d_in[0];
    const void*  ei  = d_in[1];
    const float* Ws  = (const float*)d_in[2];
    const float* bsv = (const float*)d_in[3];
    const float* Wn  = (const float*)d_in[4];
    const float* bnv = (const float*)d_in[5];

    const int M = in_sizes[0] / DD;      // 50000 nodes
    const int E = in_sizes[1] / 2;       // 800000 edges
    float* out = (float*)d_out;

    char* ws = (char*)d_ws;
    int* flag = (int*)ws;                                   // 256 B
    float* Wts = (float*)(ws + 256);                        // 64 KB
    float* Wtn = Wts + DD * DD;                             // 64 KB
    size_t o = 256 + (size_t)2 * DD * DD * sizeof(float);

    // CSR arrays
    int* deg    = (int*)(ws + o);           o += (size_t)M * 4;        // N
    int* cursor = (int*)(ws + o);           o += (size_t)M * 4;        // N (adjacent to deg -> one memset)
    int* off    = (int*)(ws + o);           o += (size_t)(M + 1) * 4;  // N+1
    int* bsum   = (int*)(ws + o);           o += 1024 * 4;
    int* list   = (int*)(ws + o);           o += (size_t)2 * E * 4;    // 2E
    size_t csr_need = o;
    size_t nei_bytes = (size_t)M * DD * sizeof(float);
    bool csr_ok = ws_size >= csr_need;
    float* nei = (ws_size >= csr_need + nei_bytes) ? (float*)(ws + csr_need)
                                                   : out;   // in-place OK

    detect_kernel<<<1, 64, 0, stream>>>((const unsigned long long*)ei,
                                        E < 64 ? E : 64, flag);
    transpose_kernel<<<(2 * DD * DD + 255) / 256, 256, 0, stream>>>(Ws, Wn, Wts, Wtn);

    if (csr_ok) {
        hipMemsetAsync(deg, 0, (size_t)2 * M * 4, stream);  // deg + cursor
        int twoE = 2 * E;
        hist_kernel<<<(twoE + 255) / 256, 256, 0, stream>>>(ei, deg, E, flag);
        int NB = (M + 1023) / 1024;
        scan1_kernel<<<NB, 256, 0, stream>>>(deg, off, bsum, M);
        scan2_kernel<<<1, 256, 0, stream>>>(bsum, NB, &off[M]);
        scan3_kernel<<<(M + 255) / 256, 256, 0, stream>>>(off, bsum, M);
        fill_kernel<<<(twoE + 255) / 256, 256, 0, stream>>>(ei, off, cursor, list, E, flag);
        int gb = (M + 3) / 4;   // 4 waves (nodes) per 256-thread block
        gather_kernel<<<gb, 256, 0, stream>>>(fea, off, list, nei, M);
    } else {
        if (nei == out) { /* fallback accumulates in out */ }
        hipMemsetAsync(nei, 0, nei_bytes, stream);
        long long rows = 2LL * E;
        int sblocks = (int)((rows + 7) / 8);
        scatter_kernel<<<sblocks, 256, 0, stream>>>(fea, ei, nei, E, flag);
    }

    int gblocks = (M + BM - 1) / BM;
    gemm_kernel<<<gblocks, 256, 0, stream>>>(fea, nei, Wts, Wtn, bsv, bnv, out, M);
}

// Round 5
// 342.052 us; speedup vs baseline: 8.4580x; 1.3801x over previous
//
#include <hip/hip_runtime.h>

#define DD 128   // feature dim (in == out)
#define BM 64    // fp32-fallback GEMM rows per block
#define BK 32    // fp32-fallback GEMM k-tile

typedef __attribute__((ext_vector_type(8))) short bf16x8;
typedef __attribute__((ext_vector_type(4))) float f32x4;

// ---------------------------------------------------------------------------
// fp32 -> bf16 round-to-nearest-even (bit trick)
__device__ __forceinline__ unsigned short f2b(float x) {
    unsigned u = __float_as_uint(x);
    u += 0x7fffu + ((u >> 16) & 1u);
    return (unsigned short)(u >> 16);
}
__device__ __forceinline__ float b2f_lo(unsigned v) {   // low bf16 of a packed u32
    return __uint_as_float(v << 16);
}
__device__ __forceinline__ float b2f_hi(unsigned v) {   // high bf16
    return __uint_as_float(v & 0xffff0000u);
}

// ---------------------------------------------------------------------------
// Detect int32 vs int64 delivery of edge_index (parallel ballot).
__global__ void detect_kernel(const unsigned long long* __restrict__ ei,
                              int n64, int* __restrict__ flag) {
    int i = threadIdx.x;  // 64 threads
    bool big = (i < n64) && (ei[i] >= (1ULL << 32));
    unsigned long long b = __ballot(big);
    if (i == 0) *flag = (b == 0ULL) ? 1 : 0;   // 1 = int64, 0 = int32
}

// ---------------------------------------------------------------------------
// fea fp32 -> bf16, 4 elems/thread
__global__ void cvt_fea_kernel(const float* __restrict__ in,
                               unsigned short* __restrict__ out, int n4) {
    int i = blockIdx.x * 256 + threadIdx.x;
    if (i >= n4) return;
    float4 v = reinterpret_cast<const float4*>(in)[i];
    ushort4 o;
    o.x = f2b(v.x); o.y = f2b(v.y); o.z = f2b(v.z); o.w = f2b(v.w);
    reinterpret_cast<ushort4*>(out)[i] = o;
}

// Wcat[n][k] (bf16, [128][256]): k<128 -> Ws[n][k], else Wn[n][k-128]
__global__ void cvt_w_kernel(const float* __restrict__ Ws,
                             const float* __restrict__ Wn,
                             unsigned short* __restrict__ Wcat) {
    int i = blockIdx.x * 256 + threadIdx.x;   // 0..32767
    int n = i >> 8, k = i & 255;
    float v = (k < DD) ? Ws[n * DD + k] : Wn[n * DD + (k - DD)];
    Wcat[i] = f2b(v);
}

// ---------------------------------------------------------------------------
// fp32-fallback weight transpose
__global__ void transpose_kernel(const float* __restrict__ Ws,
                                 const float* __restrict__ Wn,
                                 float* __restrict__ Wts,
                                 float* __restrict__ Wtn) {
    int idx = blockIdx.x * blockDim.x + threadIdx.x;
    int i = idx & (DD * DD - 1);
    int col = i >> 7;
    int k = i & (DD - 1);
    if (idx < DD * DD)          Wts[k * DD + col] = Ws[i];
    else if (idx < 2 * DD * DD) Wtn[k * DD + col] = Wn[i];
}

// ---------------------------------------------------------------------------
// Per-edge degree histogram: deg[s]++, deg[d]++ (symmetrized graph).
__global__ void hist_kernel(const void* __restrict__ ei_raw,
                            int* __restrict__ deg, int E,
                            const int* __restrict__ flag) {
    int e = blockIdx.x * 256 + threadIdx.x;
    if (e >= E) return;
    int s, d;
    if (*flag) {
        const long long* ei = (const long long*)ei_raw;
        s = (int)ei[e]; d = (int)ei[e + E];
    } else {
        const int* ei = (const int*)ei_raw;
        s = ei[e]; d = ei[e + E];
    }
    atomicAdd(&deg[s], 1);
    atomicAdd(&deg[d], 1);
}

// ---------------------------------------------------------------------------
// Exclusive scan of deg[N] -> off[N], 1024 elems per block.
__global__ void scan1_kernel(const int* __restrict__ deg, int* __restrict__ off,
                             int* __restrict__ bsum, int N) {
    __shared__ int sd[256];
    int base = blockIdx.x * 1024;
    int t = threadIdx.x;
    int v[4]; int s = 0;
#pragma unroll
    for (int j = 0; j < 4; ++j) {
        int idx = base + t * 4 + j;
        v[j] = (idx < N) ? deg[idx] : 0;
        s += v[j];
    }
    sd[t] = s; __syncthreads();
    for (int o = 1; o < 256; o <<= 1) {
        int x = (t >= o) ? sd[t - o] : 0;
        __syncthreads();
        sd[t] += x;
        __syncthreads();
    }
    int run = sd[t] - s;
    if (t == 255) bsum[blockIdx.x] = sd[255];
#pragma unroll
    for (int j = 0; j < 4; ++j) {
        int idx = base + t * 4 + j;
        if (idx < N) off[idx] = run;
        run += v[j];
    }
}

__global__ void scan2_kernel(int* __restrict__ bsum, int NB,
                             int* __restrict__ total) {
    __shared__ int sd[256];
    int t = threadIdx.x;
    int v = (t < NB) ? bsum[t] : 0;
    sd[t] = v; __syncthreads();
    for (int o = 1; o < 256; o <<= 1) {
        int x = (t >= o) ? sd[t - o] : 0;
        __syncthreads();
        sd[t] += x;
        __syncthreads();
    }
    if (t < NB) bsum[t] = sd[t] - v;
    if (t == 255) *total = sd[255];
}

__global__ void scan3_kernel(int* __restrict__ off, const int* __restrict__ bsum,
                             int N) {
    int i = blockIdx.x * blockDim.x + threadIdx.x;
    if (i < N) off[i] += bsum[i >> 10];
}

// ---------------------------------------------------------------------------
// Per-edge bucket fill: append s to d's list and d to s's list.
__global__ void fill_kernel(const void* __restrict__ ei_raw,
                            const int* __restrict__ off,
                            int* __restrict__ cursor, int* __restrict__ list,
                            int E, const int* __restrict__ flag) {
    int e = blockIdx.x * 256 + threadIdx.x;
    if (e >= E) return;
    int s, d;
    if (*flag) {
        const long long* ei = (const long long*)ei_raw;
        s = (int)ei[e]; d = (int)ei[e + E];
    } else {
        const int* ei = (const int*)ei_raw;
        s = ei[e]; d = ei[e + E];
    }
    int p0 = atomicAdd(&cursor[d], 1); list[off[d] + p0] = s;
    int p1 = atomicAdd(&cursor[s], 1); list[off[s] + p1] = d;
}

// ---------------------------------------------------------------------------
// bf16 gather: one wave per node; lane holds 2 channels (fp32 accum).
__launch_bounds__(256)
__global__ void gather_b_kernel(const unsigned short* __restrict__ feaB,
                                const int* __restrict__ off,
                                const int* __restrict__ list,
                                unsigned short* __restrict__ neiB, int N) {
    int w = (int)((blockIdx.x * 256 + threadIdx.x) >> 6);
    if (w >= N) return;
    int lane = threadIdx.x & 63;
    int start = off[w], end = off[w + 1];
    float ax = 0.f, ay = 0.f;
    const unsigned short* base = feaB + lane * 2;
    int j = start;
    for (; j + 4 <= end; j += 4) {
        int s0 = list[j], s1 = list[j + 1], s2 = list[j + 2], s3 = list[j + 3];
        unsigned a = *reinterpret_cast<const unsigned*>(base + (size_t)s0 * DD);
        unsigned b = *reinterpret_cast<const unsigned*>(base + (size_t)s1 * DD);
        unsigned c = *reinterpret_cast<const unsigned*>(base + (size_t)s2 * DD);
        unsigned d = *reinterpret_cast<const unsigned*>(base + (size_t)s3 * DD);
        ax += b2f_lo(a) + b2f_lo(b) + b2f_lo(c) + b2f_lo(d);
        ay += b2f_hi(a) + b2f_hi(b) + b2f_hi(c) + b2f_hi(d);
    }
    for (; j < end; ++j) {
        unsigned a = *reinterpret_cast<const unsigned*>(base + (size_t)list[j] * DD);
        ax += b2f_lo(a); ay += b2f_hi(a);
    }
    ushort2 o; o.x = f2b(ax); o.y = f2b(ay);
    *reinterpret_cast<ushort2*>(neiB + (size_t)w * DD + lane * 2) = o;
}

// fp32 gather (tier-2 fallback)
__launch_bounds__(256)
__global__ void gather_f32_kernel(const float* __restrict__ fea,
                                  const int* __restrict__ off,
                                  const int* __restrict__ list,
                                  float* __restrict__ nei, int N) {
    int w = (int)((blockIdx.x * 256 + threadIdx.x) >> 6);
    if (w >= N) return;
    int lane = threadIdx.x & 63;
    int start = off[w], end = off[w + 1];
    float2 acc = make_float2(0.f, 0.f);
    const float* base = fea + (size_t)lane * 2;
    int j = start;
    for (; j + 4 <= end; j += 4) {
        int s0 = list[j], s1 = list[j + 1], s2 = list[j + 2], s3 = list[j + 3];
        float2 a = *reinterpret_cast<const float2*>(base + (size_t)s0 * DD);
        float2 b = *reinterpret_cast<const float2*>(base + (size_t)s1 * DD);
        float2 c = *reinterpret_cast<const float2*>(base + (size_t)s2 * DD);
        float2 e = *reinterpret_cast<const float2*>(base + (size_t)s3 * DD);
        acc.x += a.x + b.x + c.x + e.x;
        acc.y += a.y + b.y + c.y + e.y;
    }
    for (; j < end; ++j) {
        float2 a = *reinterpret_cast<const float2*>(base + (size_t)list[j] * DD);
        acc.x += a.x; acc.y += a.y;
    }
    *reinterpret_cast<float2*>(nei + (size_t)w * DD + lane * 2) = acc;
}

// ---------------------------------------------------------------------------
// tier-3 fallback: symmetrized atomic scatter
__global__ void scatter_kernel(const float* __restrict__ fea,
                               const void* __restrict__ ei_raw,
                               float* __restrict__ nei,
                               int E, const int* __restrict__ flag) {
    long long r = (long long)blockIdx.x * 8 + (threadIdx.x >> 5);
    if (r >= 2LL * E) return;
    int lr = threadIdx.x & 31;
    int i = (int)(r < E ? r : r - E);
    int s, d;
    if (*flag) {
        const long long* ei = (const long long*)ei_raw;
        s = (int)ei[i]; d = (int)ei[i + E];
    } else {
        const int* ei = (const int*)ei_raw;
        s = ei[i]; d = ei[i + E];
    }
    if (r >= E) { int t = s; s = d; d = t; }
    const float4 v = *reinterpret_cast<const float4*>(fea + (size_t)s * DD + lr * 4);
    float* p = nei + (size_t)d * DD + lr * 4;
    unsafeAtomicAdd(p + 0, v.x);
    unsafeAtomicAdd(p + 1, v.y);
    unsafeAtomicAdd(p + 2, v.z);
    unsafeAtomicAdd(p + 3, v.w);
}

// ---------------------------------------------------------------------------
// bf16 MFMA GEMM: out[M][128] = [feaB|neiB] (K=256) @ Wcat^T + (bs+bn)
// Wcat is [N=128][K=256] bf16 row-major. Block: 4 waves; wave = 32 rows x 64
// cols; grid.y splits the 128 cols in 2. Fragments (m89-verified mapping):
//   A: row = lane&15, k = (lane>>4)*8 + j   (contiguous 16B per lane)
//   B: col = lane&15, k = (lane>>4)*8 + j   (contiguous 16B in Wcat row)
//   D: col = lane&15, row = (lane>>4)*4 + reg
__launch_bounds__(256)
__global__ void gemm_mfma_kernel(const unsigned short* __restrict__ feaB,
                                 const unsigned short* __restrict__ neiB,
                                 const unsigned short* __restrict__ Wcat,
                                 const float* __restrict__ bs,
                                 const float* __restrict__ bn,
                                 float* __restrict__ out, int M) {
    const int w  = threadIdx.x >> 6;   // wave 0..3
    const int l  = threadIdx.x & 63;
    const int lr = l & 15;
    const int ks = l >> 4;             // 0..3
    const int row0 = blockIdx.x * 128 + w * 32;
    const int col0 = blockIdx.y * 64;

    f32x4 acc[2][4] = {};

#pragma unroll
    for (int kb = 0; kb < 256; kb += 32) {
        const unsigned short* A = (kb < DD) ? feaB : neiB;
        const int klocal = (kb < DD) ? kb : kb - DD;
        bf16x8 a[2];
#pragma unroll
        for (int ri = 0; ri < 2; ++ri) {
            int rowg = row0 + ri * 16 + lr;
            if (rowg < M)
                a[ri] = *reinterpret_cast<const bf16x8*>(
                    A + (size_t)rowg * DD + klocal + ks * 8);
            else
                a[ri] = bf16x8{0, 0, 0, 0, 0, 0, 0, 0};
        }
#pragma unroll
        for (int ci = 0; ci < 4; ++ci) {
            int n = col0 + ci * 16 + lr;
            bf16x8 b = *reinterpret_cast<const bf16x8*>(
                Wcat + (size_t)n * 256 + kb + ks * 8);
#pragma unroll
            for (int ri = 0; ri < 2; ++ri)
                acc[ri][ci] = __builtin_amdgcn_mfma_f32_16x16x32_bf16(
                    a[ri], b, acc[ri][ci], 0, 0, 0);
        }
    }

#pragma unroll
    for (int ci = 0; ci < 4; ++ci) {
        int colg = col0 + ci * 16 + lr;
        float bias = bs[colg] + bn[colg];
#pragma unroll
        for (int ri = 0; ri < 2; ++ri) {
            int rbase = row0 + ri * 16 + ks * 4;
#pragma unroll
            for (int i = 0; i < 4; ++i) {
                int rowg = rbase + i;
                if (rowg < M)
                    out[(size_t)rowg * DD + colg] = acc[ri][ci][i] + bias;
            }
        }
    }
}

// ---------------------------------------------------------------------------
// fp32 fallback GEMM (round-4 proven)
__launch_bounds__(256)
__global__ void gemm_kernel(const float* __restrict__ fea,
                            const float* __restrict__ nei,
                            const float* __restrict__ Wts,
                            const float* __restrict__ Wtn,
                            const float* __restrict__ bs,
                            const float* __restrict__ bn,
                            float* __restrict__ out, int M) {
    __shared__ float Fs[BM][BK + 4];
    __shared__ float Ns[BM][BK + 4];
    __shared__ float WsT[BK][DD];
    __shared__ float WnT[BK][DD];

    const int t = threadIdx.x;
    const int cg = t & 31;
    const int rg = t >> 5;
    const int row0 = blockIdx.x * BM;

    float4 acc[8];
#pragma unroll
    for (int r = 0; r < 8; ++r) acc[r] = make_float4(0.f, 0.f, 0.f, 0.f);

    for (int kb = 0; kb < DD; kb += BK) {
#pragma unroll
        for (int j = 0; j < 2; ++j) {
            int idx = t + j * 256;
            int row = idx >> 3;
            int seg = idx & 7;
            int grow = row0 + row;
            float4 fv = make_float4(0.f, 0.f, 0.f, 0.f);
            float4 nv = make_float4(0.f, 0.f, 0.f, 0.f);
            if (grow < M) {
                fv = *reinterpret_cast<const float4*>(fea + (size_t)grow * DD + kb + seg * 4);
                nv = *reinterpret_cast<const float4*>(nei + (size_t)grow * DD + kb + seg * 4);
            }
            *reinterpret_cast<float4*>(&Fs[row][seg * 4]) = fv;
            *reinterpret_cast<float4*>(&Ns[row][seg * 4]) = nv;
        }
#pragma unroll
        for (int j = 0; j < 4; ++j) {
            int idx = t + j * 256;
            int kk = idx >> 5;
            int seg = idx & 31;
            *reinterpret_cast<float4*>(&WsT[kk][seg * 4]) =
                *reinterpret_cast<const float4*>(Wts + (size_t)(kb + kk) * DD + seg * 4);
            *reinterpret_cast<float4*>(&WnT[kk][seg * 4]) =
                *reinterpret_cast<const float4*>(Wtn + (size_t)(kb + kk) * DD + seg * 4);
        }
        __syncthreads();

#pragma unroll
        for (int kk = 0; kk < BK; ++kk) {
            float4 wsv = *reinterpret_cast<const float4*>(&WsT[kk][cg * 4]);
            float4 wnv = *reinterpret_cast<const float4*>(&WnT[kk][cg * 4]);
#pragma unroll
            for (int r = 0; r < 8; ++r) {
                float a = Fs[rg * 8 + r][kk];
                float b = Ns[rg * 8 + r][kk];
                acc[r].x += a * wsv.x + b * wnv.x;
                acc[r].y += a * wsv.y + b * wnv.y;
                acc[r].z += a * wsv.z + b * wnv.z;
                acc[r].w += a * wsv.w + b * wnv.w;
            }
        }
        __syncthreads();
    }

    float4 bsv = *reinterpret_cast<const float4*>(bs + cg * 4);
    float4 bnv = *reinterpret_cast<const float4*>(bn + cg * 4);
    float4 bias = make_float4(bsv.x + bnv.x, bsv.y + bnv.y, bsv.z + bnv.z, bsv.w + bnv.w);
#pragma unroll
    for (int r = 0; r < 8; ++r) {
        int grow = row0 + rg * 8 + r;
        if (grow < M) {
            float4 o = make_float4(acc[r].x + bias.x, acc[r].y + bias.y,
                                   acc[r].z + bias.z, acc[r].w + bias.w);
            *reinterpret_cast<float4*>(out + (size_t)grow * DD + cg * 4) = o;
        }
    }
}

// ---------------------------------------------------------------------------
extern "C" void kernel_launch(void* const* d_in, const int* in_sizes, int n_in,
                              void* d_out, int out_size, void* d_ws, size_t ws_size,
                              hipStream_t stream) {
    const float* fea = (const float*)d_in[0];
    const void*  ei  = d_in[1];
    const float* Ws  = (const float*)d_in[2];
    const float* bsv = (const float*)d_in[3];
    const float* Wn  = (const float*)d_in[4];
    const float* bnv = (const float*)d_in[5];

    const int M = in_sizes[0] / DD;      // 50000
    const int E = in_sizes[1] / 2;       // 800000
    float* out = (float*)d_out;
    char* ws = (char*)d_ws;
    int* flag = (int*)ws;

    const size_t csr_bytes = (size_t)M * 8 + (size_t)(M + 1) * 4 + 4096
                           + (size_t)2 * E * 4;

    // tier-1 layout: flag | Wcat(64KB) | feaB | neiB | csr
    size_t o1 = 256;
    unsigned short* Wcat = (unsigned short*)(ws + o1); o1 += (size_t)DD * 256 * 2;
    unsigned short* feaB = (unsigned short*)(ws + o1); o1 += (size_t)M * DD * 2;
    unsigned short* neiB = (unsigned short*)(ws + o1); o1 += (size_t)M * DD * 2;
    size_t need1 = o1 + csr_bytes;

    // tier-2/3 layout: flag | Wts | Wtn | csr
    size_t o2 = 256;
    float* Wts = (float*)(ws + o2); o2 += (size_t)DD * DD * 4;
    float* Wtn = (float*)(ws + o2); o2 += (size_t)DD * DD * 4;
    size_t need2 = o2 + csr_bytes;

    detect_kernel<<<1, 64, 0, stream>>>((const unsigned long long*)ei,
                                        E < 64 ? E : 64, flag);

    const int NB = (M + 1023) / 1024;
    const int eb = (E + 255) / 256;

    if (ws_size >= need1) {
        // ---- tier 1: bf16 gather + MFMA GEMM ----
        int* deg    = (int*)(ws + o1);
        int* cursor = deg + M;
        int* off    = cursor + M;
        int* bsum   = off + (M + 1);
        int* list   = bsum + 1024;

        int n4 = M * DD / 4;
        cvt_fea_kernel<<<(n4 + 255) / 256, 256, 0, stream>>>(fea, feaB, n4);
        cvt_w_kernel<<<(DD * 256 + 255) / 256, 256, 0, stream>>>(Ws, Wn, Wcat);
        hipMemsetAsync(deg, 0, (size_t)2 * M * 4, stream);
        hist_kernel<<<eb, 256, 0, stream>>>(ei, deg, E, flag);
        scan1_kernel<<<NB, 256, 0, stream>>>(deg, off, bsum, M);
        scan2_kernel<<<1, 256, 0, stream>>>(bsum, NB, &off[M]);
        scan3_kernel<<<(M + 255) / 256, 256, 0, stream>>>(off, bsum, M);
        fill_kernel<<<eb, 256, 0, stream>>>(ei, off, cursor, list, E, flag);
        gather_b_kernel<<<(M + 3) / 4, 256, 0, stream>>>(feaB, off, list, neiB, M);
        dim3 g((M + 127) / 128, 2);
        gemm_mfma_kernel<<<g, 256, 0, stream>>>(feaB, neiB, Wcat, bsv, bnv, out, M);
    } else if (ws_size >= need2) {
        // ---- tier 2: fp32 CSR gather (nei in out, in-place GEMM) ----
        int* deg    = (int*)(ws + o2);
        int* cursor = deg + M;
        int* off    = cursor + M;
        int* bsum   = off + (M + 1);
        int* list   = bsum + 1024;
        float* nei = out;

        transpose_kernel<<<(2 * DD * DD + 255) / 256, 256, 0, stream>>>(Ws, Wn, Wts, Wtn);
        hipMemsetAsync(deg, 0, (size_t)2 * M * 4, stream);
        hist_kernel<<<eb, 256, 0, stream>>>(ei, deg, E, flag);
        scan1_kernel<<<NB, 256, 0, stream>>>(deg, off, bsum, M);
        scan2_kernel<<<1, 256, 0, stream>>>(bsum, NB, &off[M]);
        scan3_kernel<<<(M + 255) / 256, 256, 0, stream>>>(off, bsum, M);
        fill_kernel<<<eb, 256, 0, stream>>>(ei, off, cursor, list, E, flag);
        gather_f32_kernel<<<(M + 3) / 4, 256, 0, stream>>>(fea, off, list, nei, M);
        gemm_kernel<<<(M + BM - 1) / BM, 256, 0, stream>>>(fea, nei, Wts, Wtn,
                                                           bsv, bnv, out, M);
    } else {
        // ---- tier 3: atomic scatter (nei in out, in-place GEMM) ----
        float* nei = out;
        transpose_kernel<<<(2 * DD * DD + 255) / 256, 256, 0, stream>>>(Ws, Wn, Wts, Wtn);
        hipMemsetAsync(nei, 0, (size_t)M * DD * 4, stream);
        long long rows = 2LL * E;
        int sblocks = (int)((rows + 7) / 8);
        scatter_kernel<<<sblocks, 256, 0, stream>>>(fea, ei, nei, E, flag);
        gemm_kernel<<<(M + BM - 1) / BM, 256, 0, stream>>>(fea, nei, Wts, Wtn,
                                                           bsv, bnv, out, M);
    }
}